// Round 5
// baseline (3242.257 us; speedup 1.0000x reference)
//
#include <hip/hip_runtime.h>
#include <hip/hip_bf16.h>

typedef unsigned short u16;

#define NN 4096
#define SS 1024
#define NSAMP 32
#define NGRP 16384            // 16*1024 groups
#define ROWS 524288           // NGRP*NSAMP
#define BN_EPS_F 1e-5f
#define INV_ROWS (1.0f/524288.0f)

__device__ __forceinline__ unsigned long long shflx64(unsigned long long v, int m){
    unsigned int lo = (unsigned int)v, hi = (unsigned int)(v >> 32);
    lo = __shfl_xor(lo, m, 64);
    hi = __shfl_xor(hi, m, 64);
    return ((unsigned long long)hi << 32) | lo;
}

// ---------------- zero the 512-float stats block ----------------
__global__ void zero_kernel(float* p){
    p[threadIdx.x] = 0.0f;   // launched with 512 threads
}

// ---------------- FPS: one block per batch; writes new_xyz f32 directly into out ----------------
__global__ __launch_bounds__(1024) void fps_kernel(const float* __restrict__ xyz,
                                                   float* __restrict__ out){
    __shared__ float xs[NN], ys[NN], zs[NN];
    __shared__ unsigned long long red[2][16];
    const int b = blockIdx.x;
    const int tid = threadIdx.x;
    const float* xb = xyz + (size_t)b * NN * 3;
    for (int i = tid; i < NN; i += 1024){
        xs[i] = xb[i*3+0];
        ys[i] = xb[i*3+1];
        zs[i] = xb[i*3+2];
    }
    float d0 = 1e10f, d1 = 1e10f, d2 = 1e10f, d3 = 1e10f;   // ref init 1e10 (exact f32)
    int cur = 0;
    __syncthreads();
    if (tid == 0){  // fps_idx[b,0] == 0 (scan emits carry before update)
        float* of = out + (size_t)b * SS * 3;
        of[0] = xs[0]; of[1] = ys[0]; of[2] = zs[0];
    }
    const int wave = tid >> 6, lane = tid & 63;
    for (int it = 1; it < SS; ++it){
        float cx = xs[cur], cy = ys[cur], cz = zs[cur];
        unsigned long long bk = 0ull;
        // strict fp32, no fma contraction: must match numpy's ((dx*dx+dy*dy)+dz*dz) bitwise
#define FPS_STEP(dreg, P)                                                          \
        { int i = tid + (P)*1024;                                                  \
          float dx = __fsub_rn(xs[i], cx);                                         \
          float dy = __fsub_rn(ys[i], cy);                                         \
          float dz = __fsub_rn(zs[i], cz);                                         \
          float dd = __fadd_rn(__fadd_rn(__fmul_rn(dx,dx), __fmul_rn(dy,dy)),      \
                               __fmul_rn(dz,dz));                                  \
          dreg = fminf(dreg, dd);                                                  \
          unsigned long long kk = ((unsigned long long)__float_as_uint(dreg) << 32)\
                                  | (unsigned int)(NN - 1 - i);                    \
          bk = bk > kk ? bk : kk; }
        FPS_STEP(d0, 0)
        FPS_STEP(d1, 1)
        FPS_STEP(d2, 2)
        FPS_STEP(d3, 3)
#undef FPS_STEP
        #pragma unroll
        for (int off = 1; off < 64; off <<= 1){
            unsigned long long o = shflx64(bk, off);
            bk = bk > o ? bk : o;
        }
        if (lane == 0) red[it & 1][wave] = bk;
        __syncthreads();
        unsigned long long m0 = red[it & 1][0];
        #pragma unroll
        for (int w = 1; w < 16; ++w){
            unsigned long long o = red[it & 1][w];
            m0 = m0 > o ? m0 : o;
        }
        cur = (NN - 1 - (int)(m0 & 0xffffffffu)) & (NN - 1);
        if (tid == 0){
            float* of = out + ((size_t)b * SS + it) * 3;
            of[0] = xs[cur]; of[1] = ys[cur]; of[2] = zs[cur];
        }
    }
}

// ---------------- ball query: one wave per (b,s); centroids from out (f32, exact) ----------------
__global__ __launch_bounds__(256) void ballq_kernel(const float* __restrict__ xyz,
                                                    const float* __restrict__ outc,
                                                    u16* __restrict__ gidx){
    const int g = (blockIdx.x << 2) + (threadIdx.x >> 6);
    const int lane = threadIdx.x & 63;
    const int b = g >> 10;
    const float rr = 0.04f;   // np.float32 promotion of python 0.2*0.2
    const float* c = outc + (size_t)g * 3;
    float cx = c[0], cy = c[1], cz = c[2];
    float sa = __fadd_rn(__fadd_rn(__fmul_rn(cx,cx), __fmul_rn(cy,cy)), __fmul_rn(cz,cz));
    const float* xb = xyz + (size_t)b * NN * 3;
    u16* outp = gidx + (size_t)g * NSAMP;
    int count = 0, first = -1;
    for (int base = 0; base < NN && count < NSAMP; base += 64){
        int n = base + lane;
        float x = xb[n*3+0];
        float y = xb[n*3+1];
        float z = xb[n*3+2];
        // reference: sum(a^2) - 2*dot + sum(b^2), fp32, no contraction
        float sb = __fadd_rn(__fadd_rn(__fmul_rn(x,x), __fmul_rn(y,y)), __fmul_rn(z,z));
        float dt = __fadd_rn(__fadd_rn(__fmul_rn(cx,x), __fmul_rn(cy,y)), __fmul_rn(cz,z));
        float sqr = __fadd_rn(__fsub_rn(sa, __fmul_rn(2.0f, dt)), sb);
        bool within = !(sqr > rr);
        unsigned long long m = __ballot(within);
        int pos = __popcll(m & ((1ull << lane) - 1ull));
        if (within && (count + pos) < NSAMP) outp[count + pos] = (u16)n;
        if (first < 0 && m != 0ull) first = base + (__ffsll((long long)m) - 1);
        count += __popcll(m);
    }
    for (int j = count + lane; j < NSAMP; j += 64) outp[j] = (u16)first;
}

// ---------------- shared helpers ----------------
__device__ __forceinline__ void gather_row(const float* __restrict__ xyz, const float* __restrict__ pts,
                                           const float* __restrict__ outc, const u16* __restrict__ gidx,
                                           int row, float* x){
    int g = row >> 5;
    int b = row >> 15;
    int i = gidx[row];
    const float* cc = outc + (size_t)g * 3;
    const float* xp = xyz + ((size_t)b * NN + i) * 3;
    const float* pp = pts + ((size_t)b * NN + i) * 6;
    x[0] = __fsub_rn(xp[0], cc[0]);
    x[1] = __fsub_rn(xp[1], cc[1]);
    x[2] = __fsub_rn(xp[2], cc[2]);
    #pragma unroll
    for (int k = 0; k < 6; ++k) x[3+k] = pp[k];
}

__device__ __forceinline__ void bn_coef(const float* sums, const float* ssqs,
                                        const float* g, const float* bbv, int ch,
                                        float* sc, float* sh){
    float mu = sums[ch] * INV_ROWS;
    float var = fmaf(-mu, mu, ssqs[ch] * INV_ROWS);
    var = fmaxf(var, 0.0f);
    float is = rsqrtf(var + BN_EPS_F);
    float s = is * g[ch];
    sc[ch] = s;
    sh[ch] = fmaf(-mu, s, bbv[ch]);
}

// ---------------- stats1: sums/ssq of h1 (layer-1 pre-BN) ----------------
__global__ __launch_bounds__(256) void stats1_kernel(const float* __restrict__ xyz, const float* __restrict__ pts,
                                                     const float* __restrict__ outc, const u16* __restrict__ gidx,
                                                     const float* __restrict__ W0f, const float* __restrict__ b0f,
                                                     float* __restrict__ stats){
    float s[64], q[64];
    #pragma unroll
    for (int j = 0; j < 64; ++j){ s[j] = 0.f; q[j] = 0.f; }
    int base = blockIdx.x * 2048 + threadIdx.x;
    for (int r = 0; r < 8; ++r){
        float x[9];
        gather_row(xyz, pts, outc, gidx, base + r*256, x);
        #pragma unroll
        for (int j = 0; j < 64; ++j){
            float acc = b0f[j];
            #pragma unroll
            for (int k = 0; k < 9; ++k) acc = fmaf(x[k], W0f[j*9+k], acc);
            s[j] += acc; q[j] = fmaf(acc, acc, q[j]);
        }
    }
    #pragma unroll
    for (int j = 0; j < 64; ++j){
        #pragma unroll
        for (int off = 1; off < 64; off <<= 1){
            s[j] += __shfl_xor(s[j], off, 64);
            q[j] += __shfl_xor(q[j], off, 64);
        }
    }
    if ((threadIdx.x & 63) == 0){
        #pragma unroll
        for (int j = 0; j < 64; ++j){
            atomicAdd(&stats[j], s[j]);
            atomicAdd(&stats[64 + j], q[j]);
        }
    }
}

// ---------------- stats2: recompute L1 -> BN1 -> relu -> L2, sums/ssq of h2 ----------------
__global__ __launch_bounds__(256) void stats2_kernel(const float* __restrict__ xyz, const float* __restrict__ pts,
                                                     const float* __restrict__ outc, const u16* __restrict__ gidx,
                                                     const float* __restrict__ W0f, const float* __restrict__ b0f,
                                                     const float* __restrict__ W1f, const float* __restrict__ b1f,
                                                     const float* __restrict__ g0, const float* __restrict__ bb0,
                                                     float* __restrict__ stats){
    __shared__ float sc1[64], sh1[64];
    if (threadIdx.x < 64) bn_coef(stats + 0, stats + 64, g0, bb0, threadIdx.x, sc1, sh1);
    __syncthreads();
    float s[64], q[64];
    #pragma unroll
    for (int j = 0; j < 64; ++j){ s[j] = 0.f; q[j] = 0.f; }
    int base = blockIdx.x * 2048 + threadIdx.x;
    for (int r = 0; r < 8; ++r){
        float x[9];
        gather_row(xyz, pts, outc, gidx, base + r*256, x);
        float x2[64];
        #pragma unroll
        for (int j = 0; j < 64; ++j){
            float acc = b0f[j];
            #pragma unroll
            for (int k = 0; k < 9; ++k) acc = fmaf(x[k], W0f[j*9+k], acc);
            x2[j] = fmaxf(fmaf(acc, sc1[j], sh1[j]), 0.f);
        }
        #pragma unroll
        for (int ch = 0; ch < 64; ++ch){
            float acc = b1f[ch];
            #pragma unroll
            for (int k = 0; k < 64; ++k) acc = fmaf(x2[k], W1f[ch*64+k], acc);
            s[ch] += acc; q[ch] = fmaf(acc, acc, q[ch]);
        }
    }
    #pragma unroll
    for (int j = 0; j < 64; ++j){
        #pragma unroll
        for (int off = 1; off < 64; off <<= 1){
            s[j] += __shfl_xor(s[j], off, 64);
            q[j] += __shfl_xor(q[j], off, 64);
        }
    }
    if ((threadIdx.x & 63) == 0){
        #pragma unroll
        for (int j = 0; j < 64; ++j){
            atomicAdd(&stats[128 + j], s[j]);
            atomicAdd(&stats[192 + j], q[j]);
        }
    }
}

// ---------------- stats3 fused: full chain; sums/ssq(h3) + per-group premax/premin ----------------
__global__ __launch_bounds__(256) void stats3_kernel(const float* __restrict__ xyz, const float* __restrict__ pts,
                                                     const float* __restrict__ outc, const u16* __restrict__ gidx,
                                                     const float* __restrict__ W0f, const float* __restrict__ b0f,
                                                     const float* __restrict__ W1f, const float* __restrict__ b1f,
                                                     const float* __restrict__ W2f, const float* __restrict__ b2f,
                                                     const float* __restrict__ g0, const float* __restrict__ bb0,
                                                     const float* __restrict__ g1, const float* __restrict__ bb1,
                                                     float* __restrict__ stats,
                                                     float* __restrict__ pmax, float* __restrict__ pmin){
    __shared__ float sc1[64], sh1[64], sc2[64], sh2[64];
    __shared__ float accs[4][128], accq[4][128];
    if (threadIdx.x < 64){
        bn_coef(stats + 0,   stats + 64,  g0, bb0, threadIdx.x, sc1, sh1);
        bn_coef(stats + 128, stats + 192, g1, bb1, threadIdx.x, sc2, sh2);
    }
    for (int t = threadIdx.x; t < 512; t += 256){
        ((float*)accs)[t] = 0.f;
        ((float*)accq)[t] = 0.f;
    }
    __syncthreads();
    const int row = blockIdx.x * 256 + threadIdx.x;   // one row per thread; block = 8 groups
    float x[9];
    gather_row(xyz, pts, outc, gidx, row, x);
    float x2[64];
    #pragma unroll
    for (int j = 0; j < 64; ++j){
        float acc = b0f[j];
        #pragma unroll
        for (int k = 0; k < 9; ++k) acc = fmaf(x[k], W0f[j*9+k], acc);
        x2[j] = fmaxf(fmaf(acc, sc1[j], sh1[j]), 0.f);
    }
    float x3[64];
    #pragma unroll
    for (int j = 0; j < 64; ++j){
        float acc = b1f[j];
        #pragma unroll
        for (int k = 0; k < 64; ++k) acc = fmaf(x2[k], W1f[j*64+k], acc);
        x3[j] = fmaxf(fmaf(acc, sc2[j], sh2[j]), 0.f);
    }
    const int w = threadIdx.x >> 6, lane = threadIdx.x & 63;
    const int gbase = (blockIdx.x * 256 + (w << 6) + (lane & 32)) >> 5; // this half-wave's group
    for (int ch = 0; ch < 128; ++ch){
        float v = b2f[ch];
        #pragma unroll
        for (int k = 0; k < 64; ++k) v = fmaf(x3[k], W2f[ch*64+k], v);
        float sv = v, qv = v * v;
        #pragma unroll
        for (int off = 1; off < 64; off <<= 1){
            sv += __shfl_xor(sv, off, 64);
            qv += __shfl_xor(qv, off, 64);
        }
        float mx = v, mn = v;
        #pragma unroll
        for (int off = 1; off < 32; off <<= 1){
            mx = fmaxf(mx, __shfl_xor(mx, off, 64));
            mn = fminf(mn, __shfl_xor(mn, off, 64));
        }
        if (lane == 0){
            atomicAdd(&accs[w][ch], sv);
            atomicAdd(&accq[w][ch], qv);
        }
        if ((lane & 31) == 0){
            pmax[(size_t)gbase * 128 + ch] = mx;
            pmin[(size_t)gbase * 128 + ch] = mn;
        }
    }
    __syncthreads();
    if (threadIdx.x < 128){
        int ch = threadIdx.x;
        atomicAdd(&stats[256 + ch], accs[0][ch] + accs[1][ch] + accs[2][ch] + accs[3][ch]);
    } else {
        int ch = threadIdx.x - 128;
        atomicAdd(&stats[384 + ch], accq[0][ch] + accq[1][ch] + accq[2][ch] + accq[3][ch]);
    }
}

// ---------------- BN3 applied to group max/min, relu, write out region 1 (f32) ----------------
__global__ __launch_bounds__(256) void pool_kernel(const float* __restrict__ stats,
                                                   const float* __restrict__ g2, const float* __restrict__ bb2,
                                                   const float* __restrict__ pmax, const float* __restrict__ pmin,
                                                   float* __restrict__ out){
    __shared__ float sc[128], sh[128];
    if (threadIdx.x < 128) bn_coef(stats + 256, stats + 384, g2, bb2, threadIdx.x, sc, sh);
    __syncthreads();
    int o = blockIdx.x * 256 + threadIdx.x;   // o = g*128 + ch, o < NGRP*128
    int ch = o & 127;
    float a = fmaf(pmax[o], sc[ch], sh[ch]);
    float b = fmaf(pmin[o], sc[ch], sh[ch]);  // affine maps interval endpoints (sc<0 covered)
    out[NGRP * 3 + o] = fmaxf(fmaxf(a, b), 0.0f);
}

extern "C" void kernel_launch(void* const* d_in, const int* in_sizes, int n_in,
                              void* d_out, int out_size, void* d_ws, size_t ws_size,
                              hipStream_t stream){
    const float* xyz = (const float*)d_in[0];
    const float* pts = (const float*)d_in[1];
    const float* W0  = (const float*)d_in[2];
    const float* b0  = (const float*)d_in[3];
    const float* g0  = (const float*)d_in[4];
    const float* bb0 = (const float*)d_in[5];
    const float* W1  = (const float*)d_in[6];
    const float* b1  = (const float*)d_in[7];
    const float* g1  = (const float*)d_in[8];
    const float* bb1 = (const float*)d_in[9];
    const float* W2  = (const float*)d_in[10];
    const float* b2  = (const float*)d_in[11];
    const float* g2  = (const float*)d_in[12];
    const float* bb2 = (const float*)d_in[13];
    float* out = (float*)d_out;   // f32 outputs: [new_xyz 49152 | new_points 2097152]

    // ws layout (bytes): stats[512f]@0 | gidx[524288 u16]@2048 |
    //                    pmax[2097152f]@1050624 | pmin@9439232 ; total 17,827,840
    if (ws_size < 17827840u) return;
    char*  ws    = (char*)d_ws;
    float* stats = (float*)ws;
    u16*   gidx  = (u16*)  (ws + 2048);
    float* pmax  = (float*)(ws + 1050624);
    float* pmin  = (float*)(ws + 9439232);

    zero_kernel <<<1, 512, 0, stream>>>(stats);
    fps_kernel  <<<16, 1024, 0, stream>>>(xyz, out);
    ballq_kernel<<<NGRP/4, 256, 0, stream>>>(xyz, out, gidx);
    stats1_kernel<<<256, 256, 0, stream>>>(xyz, pts, out, gidx, W0, b0, stats);
    stats2_kernel<<<256, 256, 0, stream>>>(xyz, pts, out, gidx, W0, b0, W1, b1, g0, bb0, stats);
    stats3_kernel<<<ROWS/256, 256, 0, stream>>>(xyz, pts, out, gidx, W0, b0, W1, b1, W2, b2,
                                                g0, bb0, g1, bb1, stats, pmax, pmin);
    pool_kernel <<<NGRP*128/256, 256, 0, stream>>>(stats, g2, bb2, pmax, pmin, out);
}

// Round 6
// 2637.800 us; speedup vs baseline: 1.2292x; 1.2292x over previous
//
#include <hip/hip_runtime.h>
#include <hip/hip_bf16.h>

typedef unsigned short u16;

#define NN 4096
#define SS 1024
#define NSAMP 32
#define NGRP 16384            // 16*1024 groups
#define ROWS 524288           // NGRP*NSAMP
#define BN_EPS_F 1e-5f
#define INV_ROWS (1.0f/524288.0f)

__device__ __forceinline__ unsigned long long shflx64(unsigned long long v, int m){
    unsigned int lo = (unsigned int)v, hi = (unsigned int)(v >> 32);
    lo = __shfl_xor(lo, m, 64);
    hi = __shfl_xor(hi, m, 64);
    return ((unsigned long long)hi << 32) | lo;
}

// ---------------- zero the 512-float stats block ----------------
__global__ void zero_kernel(float* p){
    p[threadIdx.x] = 0.0f;   // launched with 512 threads
}

// ---------------- FPS v2: one block/batch, 256 thr, coords in registers ----------------
// v1 was LDS-pipe-bound: 16 waves x 12 ds_read/iter + redundant 16-entry reduce ~ 3000 cyc/iter.
// v2: 4 waves, 16 pts/thread in VGPRs; LDS only for centroid broadcast + 4-entry cross-wave max.
__global__ __launch_bounds__(256) void fps_kernel(const float* __restrict__ xyz,
                                                  float* __restrict__ out){
    __shared__ float xs[NN], ys[NN], zs[NN];
    __shared__ unsigned long long red[2][4];
    const int b = blockIdx.x;
    const int tid = threadIdx.x;
    const float* xb = xyz + (size_t)b * NN * 3;
    float px[16], py[16], pz[16], dreg[16];
    #pragma unroll
    for (int p = 0; p < 16; ++p){
        int i = tid + p * 256;
        float x = xb[i*3+0], y = xb[i*3+1], z = xb[i*3+2];
        px[p] = x; py[p] = y; pz[p] = z;
        xs[i] = x; ys[i] = y; zs[i] = z;
        dreg[p] = 1e10f;                      // ref init 1e10 (exact f32)
    }
    int cur = 0;
    __syncthreads();
    if (tid == 0){  // fps_idx[b,0] == 0 (scan emits carry before update)
        float* of = out + (size_t)b * SS * 3;
        of[0] = xs[0]; of[1] = ys[0]; of[2] = zs[0];
    }
    const int wave = tid >> 6, lane = tid & 63;
    for (int it = 1; it < SS; ++it){
        float cx = xs[cur], cy = ys[cur], cz = zs[cur];   // uniform LDS broadcast
        unsigned long long bk = 0ull;
        // strict fp32, no fma contraction: must match numpy's ((dx*dx+dy*dy)+dz*dz) bitwise
        #pragma unroll
        for (int p = 0; p < 16; ++p){
            float dx = __fsub_rn(px[p], cx);
            float dy = __fsub_rn(py[p], cy);
            float dz = __fsub_rn(pz[p], cz);
            float dd = __fadd_rn(__fadd_rn(__fmul_rn(dx,dx), __fmul_rn(dy,dy)),
                                 __fmul_rn(dz,dz));
            dreg[p] = fminf(dreg[p], dd);
            // key: dist bits (>=0 so uint order == float order) | inverted index for first-max tie-break
            unsigned long long kk = ((unsigned long long)__float_as_uint(dreg[p]) << 32)
                                    | (unsigned int)(NN - 1 - (tid + p * 256));
            bk = bk > kk ? bk : kk;
        }
        #pragma unroll
        for (int off = 1; off < 64; off <<= 1){
            unsigned long long o = shflx64(bk, off);
            bk = bk > o ? bk : o;
        }
        if (lane == 0) red[it & 1][wave] = bk;
        __syncthreads();                       // double-buffered red: one barrier/iter
        unsigned long long m0 = red[it & 1][0];
        #pragma unroll
        for (int w = 1; w < 4; ++w){
            unsigned long long o = red[it & 1][w];
            m0 = m0 > o ? m0 : o;
        }
        cur = (NN - 1 - (int)(m0 & 0xffffffffu)) & (NN - 1);
        if (tid == 0){
            float* of = out + ((size_t)b * SS + it) * 3;
            of[0] = xs[cur]; of[1] = ys[cur]; of[2] = zs[cur];
        }
    }
}

// ---------------- ball query: one wave per (b,s); centroids from out (f32, exact) ----------------
__global__ __launch_bounds__(256) void ballq_kernel(const float* __restrict__ xyz,
                                                    const float* __restrict__ outc,
                                                    u16* __restrict__ gidx){
    const int g = (blockIdx.x << 2) + (threadIdx.x >> 6);
    const int lane = threadIdx.x & 63;
    const int b = g >> 10;
    const float rr = 0.04f;   // np.float32 promotion of python 0.2*0.2
    const float* c = outc + (size_t)g * 3;
    float cx = c[0], cy = c[1], cz = c[2];
    float sa = __fadd_rn(__fadd_rn(__fmul_rn(cx,cx), __fmul_rn(cy,cy)), __fmul_rn(cz,cz));
    const float* xb = xyz + (size_t)b * NN * 3;
    u16* outp = gidx + (size_t)g * NSAMP;
    int count = 0, first = -1;
    for (int base = 0; base < NN && count < NSAMP; base += 64){
        int n = base + lane;
        float x = xb[n*3+0];
        float y = xb[n*3+1];
        float z = xb[n*3+2];
        // reference: sum(a^2) - 2*dot + sum(b^2), fp32, no contraction
        float sb = __fadd_rn(__fadd_rn(__fmul_rn(x,x), __fmul_rn(y,y)), __fmul_rn(z,z));
        float dt = __fadd_rn(__fadd_rn(__fmul_rn(cx,x), __fmul_rn(cy,y)), __fmul_rn(cz,z));
        float sqr = __fadd_rn(__fsub_rn(sa, __fmul_rn(2.0f, dt)), sb);
        bool within = !(sqr > rr);
        unsigned long long m = __ballot(within);
        int pos = __popcll(m & ((1ull << lane) - 1ull));
        if (within && (count + pos) < NSAMP) outp[count + pos] = (u16)n;
        if (first < 0 && m != 0ull) first = base + (__ffsll((long long)m) - 1);
        count += __popcll(m);
    }
    for (int j = count + lane; j < NSAMP; j += 64) outp[j] = (u16)first;
}

// ---------------- shared helpers ----------------
__device__ __forceinline__ void gather_row(const float* __restrict__ xyz, const float* __restrict__ pts,
                                           const float* __restrict__ outc, const u16* __restrict__ gidx,
                                           int row, float* x){
    int g = row >> 5;
    int b = row >> 15;
    int i = gidx[row];
    const float* cc = outc + (size_t)g * 3;
    const float* xp = xyz + ((size_t)b * NN + i) * 3;
    const float* pp = pts + ((size_t)b * NN + i) * 6;
    x[0] = __fsub_rn(xp[0], cc[0]);
    x[1] = __fsub_rn(xp[1], cc[1]);
    x[2] = __fsub_rn(xp[2], cc[2]);
    #pragma unroll
    for (int k = 0; k < 6; ++k) x[3+k] = pp[k];
}

__device__ __forceinline__ void bn_coef(const float* sums, const float* ssqs,
                                        const float* g, const float* bbv, int ch,
                                        float* sc, float* sh){
    float mu = sums[ch] * INV_ROWS;
    float var = fmaf(-mu, mu, ssqs[ch] * INV_ROWS);
    var = fmaxf(var, 0.0f);
    float is = rsqrtf(var + BN_EPS_F);
    float s = is * g[ch];
    sc[ch] = s;
    sh[ch] = fmaf(-mu, s, bbv[ch]);
}

// ---------------- stats1: sums/ssq of h1 (layer-1 pre-BN) ----------------
__global__ __launch_bounds__(256) void stats1_kernel(const float* __restrict__ xyz, const float* __restrict__ pts,
                                                     const float* __restrict__ outc, const u16* __restrict__ gidx,
                                                     const float* __restrict__ W0f, const float* __restrict__ b0f,
                                                     float* __restrict__ stats){
    float s[64], q[64];
    #pragma unroll
    for (int j = 0; j < 64; ++j){ s[j] = 0.f; q[j] = 0.f; }
    int base = blockIdx.x * 2048 + threadIdx.x;
    for (int r = 0; r < 8; ++r){
        float x[9];
        gather_row(xyz, pts, outc, gidx, base + r*256, x);
        #pragma unroll
        for (int j = 0; j < 64; ++j){
            float acc = b0f[j];
            #pragma unroll
            for (int k = 0; k < 9; ++k) acc = fmaf(x[k], W0f[j*9+k], acc);
            s[j] += acc; q[j] = fmaf(acc, acc, q[j]);
        }
    }
    #pragma unroll
    for (int j = 0; j < 64; ++j){
        #pragma unroll
        for (int off = 1; off < 64; off <<= 1){
            s[j] += __shfl_xor(s[j], off, 64);
            q[j] += __shfl_xor(q[j], off, 64);
        }
    }
    if ((threadIdx.x & 63) == 0){
        #pragma unroll
        for (int j = 0; j < 64; ++j){
            atomicAdd(&stats[j], s[j]);
            atomicAdd(&stats[64 + j], q[j]);
        }
    }
}

// ---------------- stats2: recompute L1 -> BN1 -> relu -> L2, sums/ssq of h2 ----------------
__global__ __launch_bounds__(256) void stats2_kernel(const float* __restrict__ xyz, const float* __restrict__ pts,
                                                     const float* __restrict__ outc, const u16* __restrict__ gidx,
                                                     const float* __restrict__ W0f, const float* __restrict__ b0f,
                                                     const float* __restrict__ W1f, const float* __restrict__ b1f,
                                                     const float* __restrict__ g0, const float* __restrict__ bb0,
                                                     float* __restrict__ stats){
    __shared__ float sc1[64], sh1[64];
    if (threadIdx.x < 64) bn_coef(stats + 0, stats + 64, g0, bb0, threadIdx.x, sc1, sh1);
    __syncthreads();
    float s[64], q[64];
    #pragma unroll
    for (int j = 0; j < 64; ++j){ s[j] = 0.f; q[j] = 0.f; }
    int base = blockIdx.x * 2048 + threadIdx.x;
    for (int r = 0; r < 8; ++r){
        float x[9];
        gather_row(xyz, pts, outc, gidx, base + r*256, x);
        float x2[64];
        #pragma unroll
        for (int j = 0; j < 64; ++j){
            float acc = b0f[j];
            #pragma unroll
            for (int k = 0; k < 9; ++k) acc = fmaf(x[k], W0f[j*9+k], acc);
            x2[j] = fmaxf(fmaf(acc, sc1[j], sh1[j]), 0.f);
        }
        #pragma unroll
        for (int ch = 0; ch < 64; ++ch){
            float acc = b1f[ch];
            #pragma unroll
            for (int k = 0; k < 64; ++k) acc = fmaf(x2[k], W1f[ch*64+k], acc);
            s[ch] += acc; q[ch] = fmaf(acc, acc, q[ch]);
        }
    }
    #pragma unroll
    for (int j = 0; j < 64; ++j){
        #pragma unroll
        for (int off = 1; off < 64; off <<= 1){
            s[j] += __shfl_xor(s[j], off, 64);
            q[j] += __shfl_xor(q[j], off, 64);
        }
    }
    if ((threadIdx.x & 63) == 0){
        #pragma unroll
        for (int j = 0; j < 64; ++j){
            atomicAdd(&stats[128 + j], s[j]);
            atomicAdd(&stats[192 + j], q[j]);
        }
    }
}

// ---------------- stats3 fused: full chain; sums/ssq(h3) + per-group premax/premin ----------------
__global__ __launch_bounds__(256) void stats3_kernel(const float* __restrict__ xyz, const float* __restrict__ pts,
                                                     const float* __restrict__ outc, const u16* __restrict__ gidx,
                                                     const float* __restrict__ W0f, const float* __restrict__ b0f,
                                                     const float* __restrict__ W1f, const float* __restrict__ b1f,
                                                     const float* __restrict__ W2f, const float* __restrict__ b2f,
                                                     const float* __restrict__ g0, const float* __restrict__ bb0,
                                                     const float* __restrict__ g1, const float* __restrict__ bb1,
                                                     float* __restrict__ stats,
                                                     float* __restrict__ pmax, float* __restrict__ pmin){
    __shared__ float sc1[64], sh1[64], sc2[64], sh2[64];
    __shared__ float accs[4][128], accq[4][128];
    if (threadIdx.x < 64){
        bn_coef(stats + 0,   stats + 64,  g0, bb0, threadIdx.x, sc1, sh1);
        bn_coef(stats + 128, stats + 192, g1, bb1, threadIdx.x, sc2, sh2);
    }
    for (int t = threadIdx.x; t < 512; t += 256){
        ((float*)accs)[t] = 0.f;
        ((float*)accq)[t] = 0.f;
    }
    __syncthreads();
    const int row = blockIdx.x * 256 + threadIdx.x;   // one row per thread; block = 8 groups
    float x[9];
    gather_row(xyz, pts, outc, gidx, row, x);
    float x2[64];
    #pragma unroll
    for (int j = 0; j < 64; ++j){
        float acc = b0f[j];
        #pragma unroll
        for (int k = 0; k < 9; ++k) acc = fmaf(x[k], W0f[j*9+k], acc);
        x2[j] = fmaxf(fmaf(acc, sc1[j], sh1[j]), 0.f);
    }
    float x3[64];
    #pragma unroll
    for (int j = 0; j < 64; ++j){
        float acc = b1f[j];
        #pragma unroll
        for (int k = 0; k < 64; ++k) acc = fmaf(x2[k], W1f[j*64+k], acc);
        x3[j] = fmaxf(fmaf(acc, sc2[j], sh2[j]), 0.f);
    }
    const int w = threadIdx.x >> 6, lane = threadIdx.x & 63;
    const int gbase = (blockIdx.x * 256 + (w << 6) + (lane & 32)) >> 5; // this half-wave's group
    for (int ch = 0; ch < 128; ++ch){
        float v = b2f[ch];
        #pragma unroll
        for (int k = 0; k < 64; ++k) v = fmaf(x3[k], W2f[ch*64+k], v);
        float sv = v, qv = v * v;
        #pragma unroll
        for (int off = 1; off < 64; off <<= 1){
            sv += __shfl_xor(sv, off, 64);
            qv += __shfl_xor(qv, off, 64);
        }
        float mx = v, mn = v;
        #pragma unroll
        for (int off = 1; off < 32; off <<= 1){
            mx = fmaxf(mx, __shfl_xor(mx, off, 64));
            mn = fminf(mn, __shfl_xor(mn, off, 64));
        }
        if (lane == 0){
            atomicAdd(&accs[w][ch], sv);
            atomicAdd(&accq[w][ch], qv);
        }
        if ((lane & 31) == 0){
            pmax[(size_t)gbase * 128 + ch] = mx;
            pmin[(size_t)gbase * 128 + ch] = mn;
        }
    }
    __syncthreads();
    if (threadIdx.x < 128){
        int ch = threadIdx.x;
        atomicAdd(&stats[256 + ch], accs[0][ch] + accs[1][ch] + accs[2][ch] + accs[3][ch]);
    } else {
        int ch = threadIdx.x - 128;
        atomicAdd(&stats[384 + ch], accq[0][ch] + accq[1][ch] + accq[2][ch] + accq[3][ch]);
    }
}

// ---------------- BN3 applied to group max/min, relu, write out region 1 (f32) ----------------
__global__ __launch_bounds__(256) void pool_kernel(const float* __restrict__ stats,
                                                   const float* __restrict__ g2, const float* __restrict__ bb2,
                                                   const float* __restrict__ pmax, const float* __restrict__ pmin,
                                                   float* __restrict__ out){
    __shared__ float sc[128], sh[128];
    if (threadIdx.x < 128) bn_coef(stats + 256, stats + 384, g2, bb2, threadIdx.x, sc, sh);
    __syncthreads();
    int o = blockIdx.x * 256 + threadIdx.x;   // o = g*128 + ch, o < NGRP*128
    int ch = o & 127;
    float a = fmaf(pmax[o], sc[ch], sh[ch]);
    float b = fmaf(pmin[o], sc[ch], sh[ch]);  // affine maps interval endpoints (sc<0 covered)
    out[NGRP * 3 + o] = fmaxf(fmaxf(a, b), 0.0f);
}

extern "C" void kernel_launch(void* const* d_in, const int* in_sizes, int n_in,
                              void* d_out, int out_size, void* d_ws, size_t ws_size,
                              hipStream_t stream){
    const float* xyz = (const float*)d_in[0];
    const float* pts = (const float*)d_in[1];
    const float* W0  = (const float*)d_in[2];
    const float* b0  = (const float*)d_in[3];
    const float* g0  = (const float*)d_in[4];
    const float* bb0 = (const float*)d_in[5];
    const float* W1  = (const float*)d_in[6];
    const float* b1  = (const float*)d_in[7];
    const float* g1  = (const float*)d_in[8];
    const float* bb1 = (const float*)d_in[9];
    const float* W2  = (const float*)d_in[10];
    const float* b2  = (const float*)d_in[11];
    const float* g2  = (const float*)d_in[12];
    const float* bb2 = (const float*)d_in[13];
    float* out = (float*)d_out;   // f32 outputs: [new_xyz 49152 | new_points 2097152]

    // ws layout (bytes): stats[512f]@0 | gidx[524288 u16]@2048 |
    //                    pmax[2097152f]@1050624 | pmin@9439232 ; total 17,827,840
    if (ws_size < 17827840u) return;
    char*  ws    = (char*)d_ws;
    float* stats = (float*)ws;
    u16*   gidx  = (u16*)  (ws + 2048);
    float* pmax  = (float*)(ws + 1050624);
    float* pmin  = (float*)(ws + 9439232);

    zero_kernel <<<1, 512, 0, stream>>>(stats);
    fps_kernel  <<<16, 256, 0, stream>>>(xyz, out);
    ballq_kernel<<<NGRP/4, 256, 0, stream>>>(xyz, out, gidx);
    stats1_kernel<<<256, 256, 0, stream>>>(xyz, pts, out, gidx, W0, b0, stats);
    stats2_kernel<<<256, 256, 0, stream>>>(xyz, pts, out, gidx, W0, b0, W1, b1, g0, bb0, stats);
    stats3_kernel<<<ROWS/256, 256, 0, stream>>>(xyz, pts, out, gidx, W0, b0, W1, b1, W2, b2,
                                                g0, bb0, g1, bb1, stats, pmax, pmin);
    pool_kernel <<<NGRP*128/256, 256, 0, stream>>>(stats, g2, bb2, pmax, pmin, out);
}

// Round 7
// 2000.386 us; speedup vs baseline: 1.6208x; 1.3186x over previous
//
#include <hip/hip_runtime.h>
#include <hip/hip_bf16.h>

typedef unsigned short u16;

#define NN 4096
#define SS 1024
#define NSAMP 32
#define NGRP 16384            // 16*1024 groups
#define ROWS 524288           // NGRP*NSAMP
#define BN_EPS_F 1e-5f
#define INV_ROWS (1.0f/524288.0f)

// ---------------- zero the 512-float stats block ----------------
__global__ void zero_kernel(float* p){
    p[threadIdx.x] = 0.0f;   // launched with 512 threads
}

// ---------------- FPS v3: DPP wave-reduce, tree key-max ----------------
// v2 was reduce-latency-bound: 12 serially-dependent ds_swizzle (u64 butterfly) ~500 cyc/iter.
// v3: max over u64 keys via DPP (VALU pipe, row_shr 1/2/4/8 + bcast15/31), winner at lane 63,
// readlane -> 1 LDS write/wave. Key = (distbits<<32)|(NN-1-idx): exact argmax, first-index ties.
#define FPS_DPP_STEP(CTRL)                                                              \
    {   int hs = __builtin_amdgcn_update_dpp((int)(bk >> 32), (int)(bk >> 32),          \
                                             CTRL, 0xf, 0xf, false);                    \
        int ls = __builtin_amdgcn_update_dpp((int)bk, (int)bk, CTRL, 0xf, 0xf, false);  \
        unsigned long long o = ((unsigned long long)(unsigned int)hs << 32)             \
                               | (unsigned int)ls;                                      \
        bk = bk > o ? bk : o; }

__global__ __launch_bounds__(256) void fps_kernel(const float* __restrict__ xyz,
                                                  float* __restrict__ out){
    __shared__ float xs[NN], ys[NN], zs[NN];
    __shared__ unsigned long long red[2][4];
    const int b = blockIdx.x;
    const int tid = threadIdx.x;
    const float* xb = xyz + (size_t)b * NN * 3;
    float px[16], py[16], pz[16], dreg[16];
    unsigned int inv[16];
    #pragma unroll
    for (int p = 0; p < 16; ++p){
        int i = tid + p * 256;
        float x = xb[i*3+0], y = xb[i*3+1], z = xb[i*3+2];
        px[p] = x; py[p] = y; pz[p] = z;
        xs[i] = x; ys[i] = y; zs[i] = z;
        dreg[p] = 1e10f;                      // ref init 1e10 (exact f32)
        inv[p] = (unsigned int)(NN - 1 - i);  // loop-invariant key low word
    }
    int cur = 0;
    __syncthreads();
    if (tid == 0){  // fps_idx[b,0] == 0 (scan emits carry before update)
        float* of = out + (size_t)b * SS * 3;
        of[0] = xs[0]; of[1] = ys[0]; of[2] = zs[0];
    }
    const int wave = tid >> 6, lane = tid & 63;
    for (int it = 1; it < SS; ++it){
        float cx = xs[cur], cy = ys[cur], cz = zs[cur];   // uniform LDS broadcast
        unsigned long long t[16];
        // strict fp32, no fma contraction: must match numpy's ((dx*dx+dy*dy)+dz*dz) bitwise
        #pragma unroll
        for (int p = 0; p < 16; ++p){
            float dx = __fsub_rn(px[p], cx);
            float dy = __fsub_rn(py[p], cy);
            float dz = __fsub_rn(pz[p], cz);
            float dd = __fadd_rn(__fadd_rn(__fmul_rn(dx,dx), __fmul_rn(dy,dy)),
                                 __fmul_rn(dz,dz));
            dreg[p] = fminf(dreg[p], dd);
            t[p] = ((unsigned long long)__float_as_uint(dreg[p]) << 32) | inv[p];
        }
        // pairwise tree (ILP) instead of serial 16-deep chain
        #pragma unroll
        for (int s = 8; s >= 1; s >>= 1)
            #pragma unroll
            for (int i2 = 0; i2 < s; ++i2)
                if (t[i2 + s] > t[i2]) t[i2] = t[i2 + s];
        unsigned long long bk = t[0];
        // DPP reduce over 64 lanes -> winner at lane 63 (VALU pipe, no DS latency)
        FPS_DPP_STEP(0x111)  // row_shr:1
        FPS_DPP_STEP(0x112)  // row_shr:2
        FPS_DPP_STEP(0x114)  // row_shr:4
        FPS_DPP_STEP(0x118)  // row_shr:8  -> lane15 of each row = row max
        FPS_DPP_STEP(0x142)  // row_bcast:15 -> lane31/63 accumulate halves
        FPS_DPP_STEP(0x143)  // row_bcast:31 -> lane63 = wave max
        unsigned int wh = (unsigned int)__builtin_amdgcn_readlane((int)(bk >> 32), 63);
        unsigned int wl = (unsigned int)__builtin_amdgcn_readlane((int)bk, 63);
        if (lane == 0) red[it & 1][wave] = ((unsigned long long)wh << 32) | wl;
        __syncthreads();                       // double-buffered red: one barrier/iter
        unsigned long long m0 = red[it & 1][0];
        #pragma unroll
        for (int w = 1; w < 4; ++w){
            unsigned long long o = red[it & 1][w];
            m0 = m0 > o ? m0 : o;
        }
        cur = (NN - 1 - (int)(m0 & 0xffffffffu)) & (NN - 1);
        if (tid == 0){
            float* of = out + ((size_t)b * SS + it) * 3;
            of[0] = xs[cur]; of[1] = ys[cur]; of[2] = zs[cur];
        }
    }
}

// ---------------- ball query: one wave per (b,s); centroids from out (f32, exact) ----------------
__global__ __launch_bounds__(256) void ballq_kernel(const float* __restrict__ xyz,
                                                    const float* __restrict__ outc,
                                                    u16* __restrict__ gidx){
    const int g = (blockIdx.x << 2) + (threadIdx.x >> 6);
    const int lane = threadIdx.x & 63;
    const int b = g >> 10;
    const float rr = 0.04f;   // np.float32 promotion of python 0.2*0.2
    const float* c = outc + (size_t)g * 3;
    float cx = c[0], cy = c[1], cz = c[2];
    float sa = __fadd_rn(__fadd_rn(__fmul_rn(cx,cx), __fmul_rn(cy,cy)), __fmul_rn(cz,cz));
    const float* xb = xyz + (size_t)b * NN * 3;
    u16* outp = gidx + (size_t)g * NSAMP;
    int count = 0, first = -1;
    for (int base = 0; base < NN && count < NSAMP; base += 64){
        int n = base + lane;
        float x = xb[n*3+0];
        float y = xb[n*3+1];
        float z = xb[n*3+2];
        // reference: sum(a^2) - 2*dot + sum(b^2), fp32, no contraction
        float sb = __fadd_rn(__fadd_rn(__fmul_rn(x,x), __fmul_rn(y,y)), __fmul_rn(z,z));
        float dt = __fadd_rn(__fadd_rn(__fmul_rn(cx,x), __fmul_rn(cy,y)), __fmul_rn(cz,z));
        float sqr = __fadd_rn(__fsub_rn(sa, __fmul_rn(2.0f, dt)), sb);
        bool within = !(sqr > rr);
        unsigned long long m = __ballot(within);
        int pos = __popcll(m & ((1ull << lane) - 1ull));
        if (within && (count + pos) < NSAMP) outp[count + pos] = (u16)n;
        if (first < 0 && m != 0ull) first = base + (__ffsll((long long)m) - 1);
        count += __popcll(m);
    }
    for (int j = count + lane; j < NSAMP; j += 64) outp[j] = (u16)first;
}

// ---------------- shared helpers ----------------
__device__ __forceinline__ void gather_row(const float* __restrict__ xyz, const float* __restrict__ pts,
                                           const float* __restrict__ outc, const u16* __restrict__ gidx,
                                           int row, float* x){
    int g = row >> 5;
    int b = row >> 15;
    int i = gidx[row];
    const float* cc = outc + (size_t)g * 3;
    const float* xp = xyz + ((size_t)b * NN + i) * 3;
    const float* pp = pts + ((size_t)b * NN + i) * 6;
    x[0] = __fsub_rn(xp[0], cc[0]);
    x[1] = __fsub_rn(xp[1], cc[1]);
    x[2] = __fsub_rn(xp[2], cc[2]);
    #pragma unroll
    for (int k = 0; k < 6; ++k) x[3+k] = pp[k];
}

__device__ __forceinline__ void bn_coef(const float* sums, const float* ssqs,
                                        const float* g, const float* bbv, int ch,
                                        float* sc, float* sh){
    float mu = sums[ch] * INV_ROWS;
    float var = fmaf(-mu, mu, ssqs[ch] * INV_ROWS);
    var = fmaxf(var, 0.0f);
    float is = rsqrtf(var + BN_EPS_F);
    float s = is * g[ch];
    sc[ch] = s;
    sh[ch] = fmaf(-mu, s, bbv[ch]);
}

// ---------------- stats1: sums/ssq of h1 (layer-1 pre-BN) ----------------
__global__ __launch_bounds__(256) void stats1_kernel(const float* __restrict__ xyz, const float* __restrict__ pts,
                                                     const float* __restrict__ outc, const u16* __restrict__ gidx,
                                                     const float* __restrict__ W0f, const float* __restrict__ b0f,
                                                     float* __restrict__ stats){
    float s[64], q[64];
    #pragma unroll
    for (int j = 0; j < 64; ++j){ s[j] = 0.f; q[j] = 0.f; }
    int base = blockIdx.x * 2048 + threadIdx.x;
    for (int r = 0; r < 8; ++r){
        float x[9];
        gather_row(xyz, pts, outc, gidx, base + r*256, x);
        #pragma unroll
        for (int j = 0; j < 64; ++j){
            float acc = b0f[j];
            #pragma unroll
            for (int k = 0; k < 9; ++k) acc = fmaf(x[k], W0f[j*9+k], acc);
            s[j] += acc; q[j] = fmaf(acc, acc, q[j]);
        }
    }
    #pragma unroll
    for (int j = 0; j < 64; ++j){
        #pragma unroll
        for (int off = 1; off < 64; off <<= 1){
            s[j] += __shfl_xor(s[j], off, 64);
            q[j] += __shfl_xor(q[j], off, 64);
        }
    }
    if ((threadIdx.x & 63) == 0){
        #pragma unroll
        for (int j = 0; j < 64; ++j){
            atomicAdd(&stats[j], s[j]);
            atomicAdd(&stats[64 + j], q[j]);
        }
    }
}

// ---------------- stats2 v2: one row/thread (no s[64]/q[64] spill), stats3-style reduce ----------------
__global__ __launch_bounds__(256) void stats2_kernel(const float* __restrict__ xyz, const float* __restrict__ pts,
                                                     const float* __restrict__ outc, const u16* __restrict__ gidx,
                                                     const float* __restrict__ W0f, const float* __restrict__ b0f,
                                                     const float* __restrict__ W1f, const float* __restrict__ b1f,
                                                     const float* __restrict__ g0, const float* __restrict__ bb0,
                                                     float* __restrict__ stats){
    __shared__ float sc1[64], sh1[64];
    __shared__ float accs[4][64], accq[4][64];
    if (threadIdx.x < 64) bn_coef(stats + 0, stats + 64, g0, bb0, threadIdx.x, sc1, sh1);
    ((float*)accs)[threadIdx.x] = 0.f;   // 4*64 = 256 slots, one per thread
    ((float*)accq)[threadIdx.x] = 0.f;
    __syncthreads();
    const int row = blockIdx.x * 256 + threadIdx.x;
    float x[9];
    gather_row(xyz, pts, outc, gidx, row, x);
    float x2[64];
    #pragma unroll
    for (int j = 0; j < 64; ++j){
        float acc = b0f[j];
        #pragma unroll
        for (int k = 0; k < 9; ++k) acc = fmaf(x[k], W0f[j*9+k], acc);
        x2[j] = fmaxf(fmaf(acc, sc1[j], sh1[j]), 0.f);
    }
    const int w = threadIdx.x >> 6, lane = threadIdx.x & 63;
    for (int ch = 0; ch < 64; ++ch){
        float acc = b1f[ch];
        #pragma unroll
        for (int k = 0; k < 64; ++k) acc = fmaf(x2[k], W1f[ch*64+k], acc);
        float sv = acc, qv = acc * acc;
        #pragma unroll
        for (int off = 1; off < 64; off <<= 1){
            sv += __shfl_xor(sv, off, 64);
            qv += __shfl_xor(qv, off, 64);
        }
        if (lane == 0){ accs[w][ch] = sv; accq[w][ch] = qv; }
    }
    __syncthreads();
    if (threadIdx.x < 64){
        int ch = threadIdx.x;
        atomicAdd(&stats[128 + ch], accs[0][ch] + accs[1][ch] + accs[2][ch] + accs[3][ch]);
    } else if (threadIdx.x < 128){
        int ch = threadIdx.x - 64;
        atomicAdd(&stats[192 + ch], accq[0][ch] + accq[1][ch] + accq[2][ch] + accq[3][ch]);
    }
}

// ---------------- stats3 fused: full chain; sums/ssq(h3) + per-group premax/premin ----------------
__global__ __launch_bounds__(256) void stats3_kernel(const float* __restrict__ xyz, const float* __restrict__ pts,
                                                     const float* __restrict__ outc, const u16* __restrict__ gidx,
                                                     const float* __restrict__ W0f, const float* __restrict__ b0f,
                                                     const float* __restrict__ W1f, const float* __restrict__ b1f,
                                                     const float* __restrict__ W2f, const float* __restrict__ b2f,
                                                     const float* __restrict__ g0, const float* __restrict__ bb0,
                                                     const float* __restrict__ g1, const float* __restrict__ bb1,
                                                     float* __restrict__ stats,
                                                     float* __restrict__ pmax, float* __restrict__ pmin){
    __shared__ float sc1[64], sh1[64], sc2[64], sh2[64];
    __shared__ float accs[4][128], accq[4][128];
    if (threadIdx.x < 64){
        bn_coef(stats + 0,   stats + 64,  g0, bb0, threadIdx.x, sc1, sh1);
        bn_coef(stats + 128, stats + 192, g1, bb1, threadIdx.x, sc2, sh2);
    }
    for (int t = threadIdx.x; t < 512; t += 256){
        ((float*)accs)[t] = 0.f;
        ((float*)accq)[t] = 0.f;
    }
    __syncthreads();
    const int row = blockIdx.x * 256 + threadIdx.x;   // one row per thread; block = 8 groups
    float x[9];
    gather_row(xyz, pts, outc, gidx, row, x);
    float x2[64];
    #pragma unroll
    for (int j = 0; j < 64; ++j){
        float acc = b0f[j];
        #pragma unroll
        for (int k = 0; k < 9; ++k) acc = fmaf(x[k], W0f[j*9+k], acc);
        x2[j] = fmaxf(fmaf(acc, sc1[j], sh1[j]), 0.f);
    }
    float x3[64];
    #pragma unroll
    for (int j = 0; j < 64; ++j){
        float acc = b1f[j];
        #pragma unroll
        for (int k = 0; k < 64; ++k) acc = fmaf(x2[k], W1f[j*64+k], acc);
        x3[j] = fmaxf(fmaf(acc, sc2[j], sh2[j]), 0.f);
    }
    const int w = threadIdx.x >> 6, lane = threadIdx.x & 63;
    const int gbase = (blockIdx.x * 256 + (w << 6) + (lane & 32)) >> 5; // this half-wave's group
    for (int ch = 0; ch < 128; ++ch){
        float v = b2f[ch];
        #pragma unroll
        for (int k = 0; k < 64; ++k) v = fmaf(x3[k], W2f[ch*64+k], v);
        float sv = v, qv = v * v;
        #pragma unroll
        for (int off = 1; off < 64; off <<= 1){
            sv += __shfl_xor(sv, off, 64);
            qv += __shfl_xor(qv, off, 64);
        }
        float mx = v, mn = v;
        #pragma unroll
        for (int off = 1; off < 32; off <<= 1){
            mx = fmaxf(mx, __shfl_xor(mx, off, 64));
            mn = fminf(mn, __shfl_xor(mn, off, 64));
        }
        if (lane == 0){
            atomicAdd(&accs[w][ch], sv);
            atomicAdd(&accq[w][ch], qv);
        }
        if ((lane & 31) == 0){
            pmax[(size_t)gbase * 128 + ch] = mx;
            pmin[(size_t)gbase * 128 + ch] = mn;
        }
    }
    __syncthreads();
    if (threadIdx.x < 128){
        int ch = threadIdx.x;
        atomicAdd(&stats[256 + ch], accs[0][ch] + accs[1][ch] + accs[2][ch] + accs[3][ch]);
    } else {
        int ch = threadIdx.x - 128;
        atomicAdd(&stats[384 + ch], accq[0][ch] + accq[1][ch] + accq[2][ch] + accq[3][ch]);
    }
}

// ---------------- BN3 applied to group max/min, relu, write out region 1 (f32) ----------------
__global__ __launch_bounds__(256) void pool_kernel(const float* __restrict__ stats,
                                                   const float* __restrict__ g2, const float* __restrict__ bb2,
                                                   const float* __restrict__ pmax, const float* __restrict__ pmin,
                                                   float* __restrict__ out){
    __shared__ float sc[128], sh[128];
    if (threadIdx.x < 128) bn_coef(stats + 256, stats + 384, g2, bb2, threadIdx.x, sc, sh);
    __syncthreads();
    int o = blockIdx.x * 256 + threadIdx.x;   // o = g*128 + ch, o < NGRP*128
    int ch = o & 127;
    float a = fmaf(pmax[o], sc[ch], sh[ch]);
    float b = fmaf(pmin[o], sc[ch], sh[ch]);  // affine maps interval endpoints (sc<0 covered)
    out[NGRP * 3 + o] = fmaxf(fmaxf(a, b), 0.0f);
}

extern "C" void kernel_launch(void* const* d_in, const int* in_sizes, int n_in,
                              void* d_out, int out_size, void* d_ws, size_t ws_size,
                              hipStream_t stream){
    const float* xyz = (const float*)d_in[0];
    const float* pts = (const float*)d_in[1];
    const float* W0  = (const float*)d_in[2];
    const float* b0  = (const float*)d_in[3];
    const float* g0  = (const float*)d_in[4];
    const float* bb0 = (const float*)d_in[5];
    const float* W1  = (const float*)d_in[6];
    const float* b1  = (const float*)d_in[7];
    const float* g1  = (const float*)d_in[8];
    const float* bb1 = (const float*)d_in[9];
    const float* W2  = (const float*)d_in[10];
    const float* b2  = (const float*)d_in[11];
    const float* g2  = (const float*)d_in[12];
    const float* bb2 = (const float*)d_in[13];
    float* out = (float*)d_out;   // f32 outputs: [new_xyz 49152 | new_points 2097152]

    // ws layout (bytes): stats[512f]@0 | gidx[524288 u16]@2048 |
    //                    pmax[2097152f]@1050624 | pmin@9439232 ; total 17,827,840
    if (ws_size < 17827840u) return;
    char*  ws    = (char*)d_ws;
    float* stats = (float*)ws;
    u16*   gidx  = (u16*)  (ws + 2048);
    float* pmax  = (float*)(ws + 1050624);
    float* pmin  = (float*)(ws + 9439232);

    zero_kernel <<<1, 512, 0, stream>>>(stats);
    fps_kernel  <<<16, 256, 0, stream>>>(xyz, out);
    ballq_kernel<<<NGRP/4, 256, 0, stream>>>(xyz, out, gidx);
    stats1_kernel<<<256, 256, 0, stream>>>(xyz, pts, out, gidx, W0, b0, stats);
    stats2_kernel<<<ROWS/256, 256, 0, stream>>>(xyz, pts, out, gidx, W0, b0, W1, b1, g0, bb0, stats);
    stats3_kernel<<<ROWS/256, 256, 0, stream>>>(xyz, pts, out, gidx, W0, b0, W1, b1, W2, b2,
                                                g0, bb0, g1, bb1, stats, pmax, pmin);
    pool_kernel <<<NGRP*128/256, 256, 0, stream>>>(stats, g2, bb2, pmax, pmin, out);
}

// Round 8
// 1991.457 us; speedup vs baseline: 1.6281x; 1.0045x over previous
//
#include <hip/hip_runtime.h>
#include <hip/hip_bf16.h>

typedef unsigned short u16;

#define NN 4096
#define SS 1024
#define NSAMP 32
#define NGRP 16384            // 16*1024 groups
#define ROWS 524288           // NGRP*NSAMP
#define BN_EPS_F 1e-5f
#define INV_ROWS (1.0f/524288.0f)

// ---------------- zero the 512-float stats block ----------------
__global__ void zero_kernel(float* p){
    p[threadIdx.x] = 0.0f;   // launched with 512 threads
}

// ---------------- FPS v4: DPP wave-reduce + interleaved-LDS centroid ----------------
// Key = (distbits<<32)|(NN-1-idx): exact argmax with first-index tie-break.
#define FPS_DPP_STEP(CTRL)                                                              \
    {   int hs = __builtin_amdgcn_update_dpp((int)(bk >> 32), (int)(bk >> 32),          \
                                             CTRL, 0xf, 0xf, false);                    \
        int ls = __builtin_amdgcn_update_dpp((int)bk, (int)bk, CTRL, 0xf, 0xf, false);  \
        unsigned long long o = ((unsigned long long)(unsigned int)hs << 32)             \
                               | (unsigned int)ls;                                      \
        bk = bk > o ? bk : o; }

__global__ __launch_bounds__(256) void fps_kernel(const float* __restrict__ xyz,
                                                  float* __restrict__ out){
    __shared__ float p4[NN][4];                 // interleaved: one ds_read_b128 per centroid
    __shared__ unsigned long long red[2][4];
    const int b = blockIdx.x;
    const int tid = threadIdx.x;
    const float* xb = xyz + (size_t)b * NN * 3;
    float px[16], py[16], pz[16], dreg[16];
    unsigned int inv[16];
    #pragma unroll
    for (int p = 0; p < 16; ++p){
        int i = tid + p * 256;
        float x = xb[i*3+0], y = xb[i*3+1], z = xb[i*3+2];
        px[p] = x; py[p] = y; pz[p] = z;
        p4[i][0] = x; p4[i][1] = y; p4[i][2] = z;
        dreg[p] = 1e10f;                      // ref init 1e10 (exact f32)
        inv[p] = (unsigned int)(NN - 1 - i);  // loop-invariant key low word
    }
    int cur = 0;                               // fps_idx[b,0] == 0 (scan emits carry pre-update)
    __syncthreads();
    const int wave = tid >> 6, lane = tid & 63;
    for (int it = 0; it < SS; ++it){
        const float4 c = *reinterpret_cast<const float4*>(p4[cur]);  // uniform b128 broadcast
        if (tid == 0){
            float* of = out + ((size_t)b * SS + it) * 3;
            of[0] = c.x; of[1] = c.y; of[2] = c.z;
        }
        if (it == SS - 1) break;
        float cx = c.x, cy = c.y, cz = c.z;
        unsigned long long t[16];
        // strict fp32, no fma contraction: must match numpy's ((dx*dx+dy*dy)+dz*dz) bitwise
        #pragma unroll
        for (int p = 0; p < 16; ++p){
            float dx = __fsub_rn(px[p], cx);
            float dy = __fsub_rn(py[p], cy);
            float dz = __fsub_rn(pz[p], cz);
            float dd = __fadd_rn(__fadd_rn(__fmul_rn(dx,dx), __fmul_rn(dy,dy)),
                                 __fmul_rn(dz,dz));
            dreg[p] = fminf(dreg[p], dd);
            t[p] = ((unsigned long long)__float_as_uint(dreg[p]) << 32) | inv[p];
        }
        #pragma unroll
        for (int s = 8; s >= 1; s >>= 1)
            #pragma unroll
            for (int i2 = 0; i2 < s; ++i2)
                if (t[i2 + s] > t[i2]) t[i2] = t[i2 + s];
        unsigned long long bk = t[0];
        FPS_DPP_STEP(0x111)  // row_shr:1
        FPS_DPP_STEP(0x112)  // row_shr:2
        FPS_DPP_STEP(0x114)  // row_shr:4
        FPS_DPP_STEP(0x118)  // row_shr:8
        FPS_DPP_STEP(0x142)  // row_bcast:15
        FPS_DPP_STEP(0x143)  // row_bcast:31 -> lane63 = wave max
        unsigned int wh = (unsigned int)__builtin_amdgcn_readlane((int)(bk >> 32), 63);
        unsigned int wl = (unsigned int)__builtin_amdgcn_readlane((int)bk, 63);
        if (lane == 0) red[it & 1][wave] = ((unsigned long long)wh << 32) | wl;
        __syncthreads();                       // double-buffered red: one barrier/iter
        unsigned long long m0 = red[it & 1][0];
        #pragma unroll
        for (int w = 1; w < 4; ++w){
            unsigned long long o = red[it & 1][w];
            m0 = m0 > o ? m0 : o;
        }
        cur = (NN - 1 - (int)(m0 & 0xffffffffu)) & (NN - 1);
    }
}

// ---------------- ball query: one wave per (b,s); centroids from out (f32, exact) ----------------
__global__ __launch_bounds__(256) void ballq_kernel(const float* __restrict__ xyz,
                                                    const float* __restrict__ outc,
                                                    u16* __restrict__ gidx){
    const int g = (blockIdx.x << 2) + (threadIdx.x >> 6);
    const int lane = threadIdx.x & 63;
    const int b = g >> 10;
    const float rr = 0.04f;   // np.float32 promotion of python 0.2*0.2
    const float* c = outc + (size_t)g * 3;
    float cx = c[0], cy = c[1], cz = c[2];
    float sa = __fadd_rn(__fadd_rn(__fmul_rn(cx,cx), __fmul_rn(cy,cy)), __fmul_rn(cz,cz));
    const float* xb = xyz + (size_t)b * NN * 3;
    u16* outp = gidx + (size_t)g * NSAMP;
    int count = 0, first = -1;
    for (int base = 0; base < NN && count < NSAMP; base += 64){
        int n = base + lane;
        float x = xb[n*3+0];
        float y = xb[n*3+1];
        float z = xb[n*3+2];
        // reference: sum(a^2) - 2*dot + sum(b^2), fp32, no contraction
        float sb = __fadd_rn(__fadd_rn(__fmul_rn(x,x), __fmul_rn(y,y)), __fmul_rn(z,z));
        float dt = __fadd_rn(__fadd_rn(__fmul_rn(cx,x), __fmul_rn(cy,y)), __fmul_rn(cz,z));
        float sqr = __fadd_rn(__fsub_rn(sa, __fmul_rn(2.0f, dt)), sb);
        bool within = !(sqr > rr);
        unsigned long long m = __ballot(within);
        int pos = __popcll(m & ((1ull << lane) - 1ull));
        if (within && (count + pos) < NSAMP) outp[count + pos] = (u16)n;
        if (first < 0 && m != 0ull) first = base + (__ffsll((long long)m) - 1);
        count += __popcll(m);
    }
    for (int j = count + lane; j < NSAMP; j += 64) outp[j] = (u16)first;
}

// ---------------- shared helpers ----------------
__device__ __forceinline__ void gather_row(const float* __restrict__ xyz, const float* __restrict__ pts,
                                           const float* __restrict__ outc, const u16* __restrict__ gidx,
                                           int row, float* x){
    int g = row >> 5;
    int b = row >> 15;
    int i = gidx[row];
    const float* cc = outc + (size_t)g * 3;
    const float* xp = xyz + ((size_t)b * NN + i) * 3;
    const float* pp = pts + ((size_t)b * NN + i) * 6;
    x[0] = __fsub_rn(xp[0], cc[0]);
    x[1] = __fsub_rn(xp[1], cc[1]);
    x[2] = __fsub_rn(xp[2], cc[2]);
    #pragma unroll
    for (int k = 0; k < 6; ++k) x[3+k] = pp[k];
}

__device__ __forceinline__ void bn_coef(const float* sums, const float* ssqs,
                                        const float* g, const float* bbv, int ch,
                                        float* sc, float* sh){
    float mu = sums[ch] * INV_ROWS;
    float var = fmaf(-mu, mu, ssqs[ch] * INV_ROWS);
    var = fmaxf(var, 0.0f);
    float is = rsqrtf(var + BN_EPS_F);
    float s = is * g[ch];
    sc[ch] = s;
    sh[ch] = fmaf(-mu, s, bbv[ch]);
}

// ---------------- stats1: sums/ssq of h1 (layer-1 pre-BN) ----------------
__global__ __launch_bounds__(256) void stats1_kernel(const float* __restrict__ xyz, const float* __restrict__ pts,
                                                     const float* __restrict__ outc, const u16* __restrict__ gidx,
                                                     const float* __restrict__ W0f, const float* __restrict__ b0f,
                                                     float* __restrict__ stats){
    float s[64], q[64];
    #pragma unroll
    for (int j = 0; j < 64; ++j){ s[j] = 0.f; q[j] = 0.f; }
    int base = blockIdx.x * 2048 + threadIdx.x;
    for (int r = 0; r < 8; ++r){
        float x[9];
        gather_row(xyz, pts, outc, gidx, base + r*256, x);
        #pragma unroll
        for (int j = 0; j < 64; ++j){
            float acc = b0f[j];
            #pragma unroll
            for (int k = 0; k < 9; ++k) acc = fmaf(x[k], W0f[j*9+k], acc);
            s[j] += acc; q[j] = fmaf(acc, acc, q[j]);
        }
    }
    #pragma unroll
    for (int j = 0; j < 64; ++j){
        #pragma unroll
        for (int off = 1; off < 64; off <<= 1){
            s[j] += __shfl_xor(s[j], off, 64);
            q[j] += __shfl_xor(q[j], off, 64);
        }
    }
    if ((threadIdx.x & 63) == 0){
        #pragma unroll
        for (int j = 0; j < 64; ++j){
            atomicAdd(&stats[j], s[j]);
            atomicAdd(&stats[64 + j], q[j]);
        }
    }
}

// ---------------- stats2 v3: LDS-transpose column reduction (no butterflies) ----------------
// v2 was 10x over VALU floor: VGPR_Count=44 proved x2[64] demotion + 768 dependent
// shuffle DS-ops/wave. v3: h2 row -> tr[256][65] (pad: 2-way banks, free), wave w /
// lane ch column-sums quarter w sequentially. 4-split dot accumulators for ILP.
__global__ __launch_bounds__(256) void stats2_kernel(const float* __restrict__ xyz, const float* __restrict__ pts,
                                                     const float* __restrict__ outc, const u16* __restrict__ gidx,
                                                     const float* __restrict__ W0f, const float* __restrict__ b0f,
                                                     const float* __restrict__ W1f, const float* __restrict__ b1f,
                                                     const float* __restrict__ g0, const float* __restrict__ bb0,
                                                     float* __restrict__ stats){
    __shared__ float sc1[64], sh1[64];
    __shared__ float tr[256 * 65];
    __shared__ float accs[4][64], accq[4][64];
    if (threadIdx.x < 64) bn_coef(stats + 0, stats + 64, g0, bb0, threadIdx.x, sc1, sh1);
    __syncthreads();
    const int row = blockIdx.x * 256 + threadIdx.x;
    float x[9];
    gather_row(xyz, pts, outc, gidx, row, x);
    float x2[64];
    #pragma unroll
    for (int j = 0; j < 64; ++j){
        float acc = b0f[j];
        #pragma unroll
        for (int k = 0; k < 9; ++k) acc = fmaf(x[k], W0f[j*9+k], acc);
        x2[j] = fmaxf(fmaf(acc, sc1[j], sh1[j]), 0.f);
    }
    for (int ch = 0; ch < 64; ++ch){
        float a0 = b1f[ch], a1 = 0.f, a2 = 0.f, a3 = 0.f;
        const float* wrow = W1f + ch * 64;
        #pragma unroll
        for (int k = 0; k < 64; k += 4){
            a0 = fmaf(x2[k+0], wrow[k+0], a0);
            a1 = fmaf(x2[k+1], wrow[k+1], a1);
            a2 = fmaf(x2[k+2], wrow[k+2], a2);
            a3 = fmaf(x2[k+3], wrow[k+3], a3);
        }
        tr[threadIdx.x * 65 + ch] = (a0 + a1) + (a2 + a3);
    }
    __syncthreads();
    const int ch = threadIdx.x & 63, qq = threadIdx.x >> 6;
    float s = 0.f, q = 0.f;
    for (int r = 0; r < 64; ++r){
        float v = tr[(qq * 64 + r) * 65 + ch];
        s += v; q = fmaf(v, v, q);
    }
    accs[qq][ch] = s; accq[qq][ch] = q;
    __syncthreads();
    if (threadIdx.x < 64){
        int c = threadIdx.x;
        atomicAdd(&stats[128 + c], (accs[0][c] + accs[1][c]) + (accs[2][c] + accs[3][c]));
    } else if (threadIdx.x < 128){
        int c = threadIdx.x - 64;
        atomicAdd(&stats[192 + c], (accq[0][c] + accq[1][c]) + (accq[2][c] + accq[3][c]));
    }
}

// ---------------- stats3 v3: full chain; transpose reduce in two 64-ch halves + group max/min ----------------
__global__ __launch_bounds__(256) void stats3_kernel(const float* __restrict__ xyz, const float* __restrict__ pts,
                                                     const float* __restrict__ outc, const u16* __restrict__ gidx,
                                                     const float* __restrict__ W0f, const float* __restrict__ b0f,
                                                     const float* __restrict__ W1f, const float* __restrict__ b1f,
                                                     const float* __restrict__ W2f, const float* __restrict__ b2f,
                                                     const float* __restrict__ g0, const float* __restrict__ bb0,
                                                     const float* __restrict__ g1, const float* __restrict__ bb1,
                                                     float* __restrict__ stats,
                                                     float* __restrict__ pmax, float* __restrict__ pmin){
    __shared__ float sc1[64], sh1[64], sc2[64], sh2[64];
    __shared__ float tr[256 * 65];
    __shared__ float accs[4][64], accq[4][64];
    if (threadIdx.x < 64){
        bn_coef(stats + 0,   stats + 64,  g0, bb0, threadIdx.x, sc1, sh1);
        bn_coef(stats + 128, stats + 192, g1, bb1, threadIdx.x, sc2, sh2);
    }
    __syncthreads();
    const int row = blockIdx.x * 256 + threadIdx.x;
    float x[9];
    gather_row(xyz, pts, outc, gidx, row, x);
    float x2[64];
    #pragma unroll
    for (int j = 0; j < 64; ++j){
        float acc = b0f[j];
        #pragma unroll
        for (int k = 0; k < 9; ++k) acc = fmaf(x[k], W0f[j*9+k], acc);
        x2[j] = fmaxf(fmaf(acc, sc1[j], sh1[j]), 0.f);
    }
    float x3[64];
    #pragma unroll
    for (int j = 0; j < 64; ++j){
        float a0 = b1f[j], a1 = 0.f, a2 = 0.f, a3 = 0.f;
        const float* wrow = W1f + j * 64;
        #pragma unroll
        for (int k = 0; k < 64; k += 4){
            a0 = fmaf(x2[k+0], wrow[k+0], a0);
            a1 = fmaf(x2[k+1], wrow[k+1], a1);
            a2 = fmaf(x2[k+2], wrow[k+2], a2);
            a3 = fmaf(x2[k+3], wrow[k+3], a3);
        }
        x3[j] = fmaxf(fmaf((a0 + a1) + (a2 + a3), sc2[j], sh2[j]), 0.f);
    }
    const int ch = threadIdx.x & 63, qq = threadIdx.x >> 6;
    for (int half = 0; half < 2; ++half){
        for (int c64 = 0; c64 < 64; ++c64){
            int c = half * 64 + c64;
            float a0 = b2f[c], a1 = 0.f, a2 = 0.f, a3 = 0.f;
            const float* wrow = W2f + c * 64;
            #pragma unroll
            for (int k = 0; k < 64; k += 4){
                a0 = fmaf(x3[k+0], wrow[k+0], a0);
                a1 = fmaf(x3[k+1], wrow[k+1], a1);
                a2 = fmaf(x3[k+2], wrow[k+2], a2);
                a3 = fmaf(x3[k+3], wrow[k+3], a3);
            }
            tr[threadIdx.x * 65 + c64] = (a0 + a1) + (a2 + a3);
        }
        __syncthreads();
        // quarter qq = rows [qq*64, qq*64+64) = groups 2qq (first 32 rows) and 2qq+1
        float s = 0.f, q = 0.f;
        float mxA = -1e30f, mnA = 1e30f, mxB = -1e30f, mnB = 1e30f;
        for (int r = 0; r < 32; ++r){
            float v = tr[(qq * 64 + r) * 65 + ch];
            s += v; q = fmaf(v, v, q);
            mxA = fmaxf(mxA, v); mnA = fminf(mnA, v);
        }
        for (int r = 32; r < 64; ++r){
            float v = tr[(qq * 64 + r) * 65 + ch];
            s += v; q = fmaf(v, v, q);
            mxB = fmaxf(mxB, v); mnB = fminf(mnB, v);
        }
        int c = half * 64 + ch;
        int gA = blockIdx.x * 8 + 2 * qq;
        pmax[(size_t)gA * 128 + c] = mxA;           // coalesced across lanes (c consecutive)
        pmin[(size_t)gA * 128 + c] = mnA;
        pmax[(size_t)(gA + 1) * 128 + c] = mxB;
        pmin[(size_t)(gA + 1) * 128 + c] = mnB;
        accs[qq][ch] = s; accq[qq][ch] = q;
        __syncthreads();
        if (threadIdx.x < 64){
            int cc = half * 64 + threadIdx.x;
            atomicAdd(&stats[256 + cc], (accs[0][threadIdx.x] + accs[1][threadIdx.x])
                                      + (accs[2][threadIdx.x] + accs[3][threadIdx.x]));
        } else if (threadIdx.x < 128){
            int t = threadIdx.x - 64;
            int cc = half * 64 + t;
            atomicAdd(&stats[384 + cc], (accq[0][t] + accq[1][t]) + (accq[2][t] + accq[3][t]));
        }
        __syncthreads();   // tr + accs reuse protection for next half
    }
}

// ---------------- BN3 applied to group max/min, relu, write out region 1 (f32) ----------------
__global__ __launch_bounds__(256) void pool_kernel(const float* __restrict__ stats,
                                                   const float* __restrict__ g2, const float* __restrict__ bb2,
                                                   const float* __restrict__ pmax, const float* __restrict__ pmin,
                                                   float* __restrict__ out){
    __shared__ float sc[128], sh[128];
    if (threadIdx.x < 128) bn_coef(stats + 256, stats + 384, g2, bb2, threadIdx.x, sc, sh);
    __syncthreads();
    int o = blockIdx.x * 256 + threadIdx.x;   // o = g*128 + ch, o < NGRP*128
    int ch = o & 127;
    float a = fmaf(pmax[o], sc[ch], sh[ch]);
    float b = fmaf(pmin[o], sc[ch], sh[ch]);  // affine maps interval endpoints (sc<0 covered)
    out[NGRP * 3 + o] = fmaxf(fmaxf(a, b), 0.0f);
}

extern "C" void kernel_launch(void* const* d_in, const int* in_sizes, int n_in,
                              void* d_out, int out_size, void* d_ws, size_t ws_size,
                              hipStream_t stream){
    const float* xyz = (const float*)d_in[0];
    const float* pts = (const float*)d_in[1];
    const float* W0  = (const float*)d_in[2];
    const float* b0  = (const float*)d_in[3];
    const float* g0  = (const float*)d_in[4];
    const float* bb0 = (const float*)d_in[5];
    const float* W1  = (const float*)d_in[6];
    const float* b1  = (const float*)d_in[7];
    const float* g1  = (const float*)d_in[8];
    const float* bb1 = (const float*)d_in[9];
    const float* W2  = (const float*)d_in[10];
    const float* b2  = (const float*)d_in[11];
    const float* g2  = (const float*)d_in[12];
    const float* bb2 = (const float*)d_in[13];
    float* out = (float*)d_out;   // f32 outputs: [new_xyz 49152 | new_points 2097152]

    // ws layout (bytes): stats[512f]@0 | gidx[524288 u16]@2048 |
    //                    pmax[2097152f]@1050624 | pmin@9439232 ; total 17,827,840
    if (ws_size < 17827840u) return;
    char*  ws    = (char*)d_ws;
    float* stats = (float*)ws;
    u16*   gidx  = (u16*)  (ws + 2048);
    float* pmax  = (float*)(ws + 1050624);
    float* pmin  = (float*)(ws + 9439232);

    zero_kernel <<<1, 512, 0, stream>>>(stats);
    fps_kernel  <<<16, 256, 0, stream>>>(xyz, out);
    ballq_kernel<<<NGRP/4, 256, 0, stream>>>(xyz, out, gidx);
    stats1_kernel<<<256, 256, 0, stream>>>(xyz, pts, out, gidx, W0, b0, stats);
    stats2_kernel<<<ROWS/256, 256, 0, stream>>>(xyz, pts, out, gidx, W0, b0, W1, b1, g0, bb0, stats);
    stats3_kernel<<<ROWS/256, 256, 0, stream>>>(xyz, pts, out, gidx, W0, b0, W1, b1, W2, b2,
                                                g0, bb0, g1, bb1, stats, pmax, pmin);
    pool_kernel <<<NGRP*128/256, 256, 0, stream>>>(stats, g2, bb2, pmax, pmin, out);
}

// Round 9
// 1873.481 us; speedup vs baseline: 1.7306x; 1.0630x over previous
//
#include <hip/hip_runtime.h>
#include <hip/hip_bf16.h>

typedef unsigned short u16;

#define NN 4096
#define SS 1024
#define NSAMP 32
#define NGRP 16384            // 16*1024 groups
#define ROWS 524288           // NGRP*NSAMP
#define BN_EPS_F 1e-5f
#define INV_ROWS (1.0f/524288.0f)

// ---------------- zero the 512-float stats block ----------------
__global__ void zero_kernel(float* p){
    p[threadIdx.x] = 0.0f;   // launched with 512 threads
}

// ---------------- FPS v3 (round-7 verbatim, measured 660us): DPP wave-reduce ----------------
// Key = (distbits<<32)|(NN-1-idx): exact argmax with first-index tie-break.
#define FPS_DPP_STEP(CTRL)                                                              \
    {   int hs = __builtin_amdgcn_update_dpp((int)(bk >> 32), (int)(bk >> 32),          \
                                             CTRL, 0xf, 0xf, false);                    \
        int ls = __builtin_amdgcn_update_dpp((int)bk, (int)bk, CTRL, 0xf, 0xf, false);  \
        unsigned long long o = ((unsigned long long)(unsigned int)hs << 32)             \
                               | (unsigned int)ls;                                      \
        bk = bk > o ? bk : o; }

__global__ __launch_bounds__(256) void fps_kernel(const float* __restrict__ xyz,
                                                  float* __restrict__ out){
    __shared__ float xs[NN], ys[NN], zs[NN];
    __shared__ unsigned long long red[2][4];
    const int b = blockIdx.x;
    const int tid = threadIdx.x;
    const float* xb = xyz + (size_t)b * NN * 3;
    float px[16], py[16], pz[16], dreg[16];
    unsigned int inv[16];
    #pragma unroll
    for (int p = 0; p < 16; ++p){
        int i = tid + p * 256;
        float x = xb[i*3+0], y = xb[i*3+1], z = xb[i*3+2];
        px[p] = x; py[p] = y; pz[p] = z;
        xs[i] = x; ys[i] = y; zs[i] = z;
        dreg[p] = 1e10f;                      // ref init 1e10 (exact f32)
        inv[p] = (unsigned int)(NN - 1 - i);  // loop-invariant key low word
    }
    int cur = 0;
    __syncthreads();
    if (tid == 0){  // fps_idx[b,0] == 0 (scan emits carry before update)
        float* of = out + (size_t)b * SS * 3;
        of[0] = xs[0]; of[1] = ys[0]; of[2] = zs[0];
    }
    const int wave = tid >> 6, lane = tid & 63;
    for (int it = 1; it < SS; ++it){
        float cx = xs[cur], cy = ys[cur], cz = zs[cur];   // uniform LDS broadcast
        unsigned long long t[16];
        // strict fp32, no fma contraction: must match numpy's ((dx*dx+dy*dy)+dz*dz) bitwise
        #pragma unroll
        for (int p = 0; p < 16; ++p){
            float dx = __fsub_rn(px[p], cx);
            float dy = __fsub_rn(py[p], cy);
            float dz = __fsub_rn(pz[p], cz);
            float dd = __fadd_rn(__fadd_rn(__fmul_rn(dx,dx), __fmul_rn(dy,dy)),
                                 __fmul_rn(dz,dz));
            dreg[p] = fminf(dreg[p], dd);
            t[p] = ((unsigned long long)__float_as_uint(dreg[p]) << 32) | inv[p];
        }
        // pairwise tree (ILP) instead of serial 16-deep chain
        #pragma unroll
        for (int s = 8; s >= 1; s >>= 1)
            #pragma unroll
            for (int i2 = 0; i2 < s; ++i2)
                if (t[i2 + s] > t[i2]) t[i2] = t[i2 + s];
        unsigned long long bk = t[0];
        // DPP reduce over 64 lanes -> winner at lane 63 (VALU pipe, no DS latency)
        FPS_DPP_STEP(0x111)  // row_shr:1
        FPS_DPP_STEP(0x112)  // row_shr:2
        FPS_DPP_STEP(0x114)  // row_shr:4
        FPS_DPP_STEP(0x118)  // row_shr:8  -> lane15 of each row = row max
        FPS_DPP_STEP(0x142)  // row_bcast:15 -> lane31/63 accumulate halves
        FPS_DPP_STEP(0x143)  // row_bcast:31 -> lane63 = wave max
        unsigned int wh = (unsigned int)__builtin_amdgcn_readlane((int)(bk >> 32), 63);
        unsigned int wl = (unsigned int)__builtin_amdgcn_readlane((int)bk, 63);
        if (lane == 0) red[it & 1][wave] = ((unsigned long long)wh << 32) | wl;
        __syncthreads();                       // double-buffered red: one barrier/iter
        unsigned long long m0 = red[it & 1][0];
        #pragma unroll
        for (int w = 1; w < 4; ++w){
            unsigned long long o = red[it & 1][w];
            m0 = m0 > o ? m0 : o;
        }
        cur = (NN - 1 - (int)(m0 & 0xffffffffu)) & (NN - 1);
        if (tid == 0){
            float* of = out + ((size_t)b * SS + it) * 3;
            of[0] = xs[cur]; of[1] = ys[cur]; of[2] = zs[cur];
        }
    }
}

// ---------------- ball query: one wave per (b,s); centroids from out (f32, exact) ----------------
__global__ __launch_bounds__(256) void ballq_kernel(const float* __restrict__ xyz,
                                                    const float* __restrict__ outc,
                                                    u16* __restrict__ gidx){
    const int g = (blockIdx.x << 2) + (threadIdx.x >> 6);
    const int lane = threadIdx.x & 63;
    const int b = g >> 10;
    const float rr = 0.04f;   // np.float32 promotion of python 0.2*0.2
    const float* c = outc + (size_t)g * 3;
    float cx = c[0], cy = c[1], cz = c[2];
    float sa = __fadd_rn(__fadd_rn(__fmul_rn(cx,cx), __fmul_rn(cy,cy)), __fmul_rn(cz,cz));
    const float* xb = xyz + (size_t)b * NN * 3;
    u16* outp = gidx + (size_t)g * NSAMP;
    int count = 0, first = -1;
    for (int base = 0; base < NN && count < NSAMP; base += 64){
        int n = base + lane;
        float x = xb[n*3+0];
        float y = xb[n*3+1];
        float z = xb[n*3+2];
        // reference: sum(a^2) - 2*dot + sum(b^2), fp32, no contraction
        float sb = __fadd_rn(__fadd_rn(__fmul_rn(x,x), __fmul_rn(y,y)), __fmul_rn(z,z));
        float dt = __fadd_rn(__fadd_rn(__fmul_rn(cx,x), __fmul_rn(cy,y)), __fmul_rn(cz,z));
        float sqr = __fadd_rn(__fsub_rn(sa, __fmul_rn(2.0f, dt)), sb);
        bool within = !(sqr > rr);
        unsigned long long m = __ballot(within);
        int pos = __popcll(m & ((1ull << lane) - 1ull));
        if (within && (count + pos) < NSAMP) outp[count + pos] = (u16)n;
        if (first < 0 && m != 0ull) first = base + (__ffsll((long long)m) - 1);
        count += __popcll(m);
    }
    for (int j = count + lane; j < NSAMP; j += 64) outp[j] = (u16)first;
}

// ---------------- shared helpers ----------------
__device__ __forceinline__ void gather_row(const float* __restrict__ xyz, const float* __restrict__ pts,
                                           const float* __restrict__ outc, const u16* __restrict__ gidx,
                                           int row, float* x){
    int g = row >> 5;
    int b = row >> 15;
    int i = gidx[row];
    const float* cc = outc + (size_t)g * 3;
    const float* xp = xyz + ((size_t)b * NN + i) * 3;
    const float* pp = pts + ((size_t)b * NN + i) * 6;
    x[0] = __fsub_rn(xp[0], cc[0]);
    x[1] = __fsub_rn(xp[1], cc[1]);
    x[2] = __fsub_rn(xp[2], cc[2]);
    #pragma unroll
    for (int k = 0; k < 6; ++k) x[3+k] = pp[k];
}

__device__ __forceinline__ void bn_coef(const float* sums, const float* ssqs,
                                        const float* g, const float* bbv, int ch,
                                        float* sc, float* sh){
    float mu = sums[ch] * INV_ROWS;
    float var = fmaf(-mu, mu, ssqs[ch] * INV_ROWS);
    var = fmaxf(var, 0.0f);
    float is = rsqrtf(var + BN_EPS_F);
    float s = is * g[ch];
    sc[ch] = s;
    sh[ch] = fmaf(-mu, s, bbv[ch]);
}

// ---------------- stats1: sums/ssq of h1 (layer-1 pre-BN) ----------------
// (256,1): min 1 wave/EU -> no occupancy-driven scratch demotion of s[]/q[]
__global__ __launch_bounds__(256, 1) void stats1_kernel(const float* __restrict__ xyz, const float* __restrict__ pts,
                                                        const float* __restrict__ outc, const u16* __restrict__ gidx,
                                                        const float* __restrict__ W0f, const float* __restrict__ b0f,
                                                        float* __restrict__ stats){
    float s[64], q[64];
    #pragma unroll
    for (int j = 0; j < 64; ++j){ s[j] = 0.f; q[j] = 0.f; }
    int base = blockIdx.x * 2048 + threadIdx.x;
    for (int r = 0; r < 8; ++r){
        float x[9];
        gather_row(xyz, pts, outc, gidx, base + r*256, x);
        #pragma unroll
        for (int j = 0; j < 64; ++j){
            float acc = b0f[j];
            #pragma unroll
            for (int k = 0; k < 9; ++k) acc = fmaf(x[k], W0f[j*9+k], acc);
            s[j] += acc; q[j] = fmaf(acc, acc, q[j]);
        }
    }
    #pragma unroll
    for (int j = 0; j < 64; ++j){
        #pragma unroll
        for (int off = 1; off < 64; off <<= 1){
            s[j] += __shfl_xor(s[j], off, 64);
            q[j] += __shfl_xor(q[j], off, 64);
        }
    }
    if ((threadIdx.x & 63) == 0){
        #pragma unroll
        for (int j = 0; j < 64; ++j){
            atomicAdd(&stats[j], s[j]);
            atomicAdd(&stats[64 + j], q[j]);
        }
    }
}

// ---------------- stats2 v4: transpose reduce + (256,1) so x2[64] stays in VGPRs ----------------
// R7 counter row VGPR_Count=44 proved x2[64] was scratch-demoted (occupancy-targeted
// allocation); its dot-loop re-reads were ~8 GB/dispatch of scratch traffic.
__global__ __launch_bounds__(256, 1) void stats2_kernel(const float* __restrict__ xyz, const float* __restrict__ pts,
                                                        const float* __restrict__ outc, const u16* __restrict__ gidx,
                                                        const float* __restrict__ W0f, const float* __restrict__ b0f,
                                                        const float* __restrict__ W1f, const float* __restrict__ b1f,
                                                        const float* __restrict__ g0, const float* __restrict__ bb0,
                                                        float* __restrict__ stats){
    __shared__ float sc1[64], sh1[64];
    __shared__ float tr[256 * 65];
    __shared__ float accs[4][64], accq[4][64];
    if (threadIdx.x < 64) bn_coef(stats + 0, stats + 64, g0, bb0, threadIdx.x, sc1, sh1);
    __syncthreads();
    const int row = blockIdx.x * 256 + threadIdx.x;
    float x[9];
    gather_row(xyz, pts, outc, gidx, row, x);
    float x2[64];
    #pragma unroll
    for (int j = 0; j < 64; ++j){
        float acc = b0f[j];
        #pragma unroll
        for (int k = 0; k < 9; ++k) acc = fmaf(x[k], W0f[j*9+k], acc);
        x2[j] = fmaxf(fmaf(acc, sc1[j], sh1[j]), 0.f);
    }
    for (int ch = 0; ch < 64; ++ch){
        float a0 = b1f[ch], a1 = 0.f, a2 = 0.f, a3 = 0.f;
        const float* wrow = W1f + ch * 64;
        #pragma unroll
        for (int k = 0; k < 64; k += 4){
            a0 = fmaf(x2[k+0], wrow[k+0], a0);
            a1 = fmaf(x2[k+1], wrow[k+1], a1);
            a2 = fmaf(x2[k+2], wrow[k+2], a2);
            a3 = fmaf(x2[k+3], wrow[k+3], a3);
        }
        tr[threadIdx.x * 65 + ch] = (a0 + a1) + (a2 + a3);
    }
    __syncthreads();
    const int ch = threadIdx.x & 63, qq = threadIdx.x >> 6;
    float s = 0.f, q = 0.f;
    for (int r = 0; r < 64; ++r){
        float v = tr[(qq * 64 + r) * 65 + ch];
        s += v; q = fmaf(v, v, q);
    }
    accs[qq][ch] = s; accq[qq][ch] = q;
    __syncthreads();
    if (threadIdx.x < 64){
        int c = threadIdx.x;
        atomicAdd(&stats[128 + c], (accs[0][c] + accs[1][c]) + (accs[2][c] + accs[3][c]));
    } else if (threadIdx.x < 128){
        int c = threadIdx.x - 64;
        atomicAdd(&stats[192 + c], (accq[0][c] + accq[1][c]) + (accq[2][c] + accq[3][c]));
    }
}

// ---------------- stats3 v4: full chain + (256,1) so x2/x3 stay in VGPRs ----------------
__global__ __launch_bounds__(256, 1) void stats3_kernel(const float* __restrict__ xyz, const float* __restrict__ pts,
                                                        const float* __restrict__ outc, const u16* __restrict__ gidx,
                                                        const float* __restrict__ W0f, const float* __restrict__ b0f,
                                                        const float* __restrict__ W1f, const float* __restrict__ b1f,
                                                        const float* __restrict__ W2f, const float* __restrict__ b2f,
                                                        const float* __restrict__ g0, const float* __restrict__ bb0,
                                                        const float* __restrict__ g1, const float* __restrict__ bb1,
                                                        float* __restrict__ stats,
                                                        float* __restrict__ pmax, float* __restrict__ pmin){
    __shared__ float sc1[64], sh1[64], sc2[64], sh2[64];
    __shared__ float tr[256 * 65];
    __shared__ float accs[4][64], accq[4][64];
    if (threadIdx.x < 64){
        bn_coef(stats + 0,   stats + 64,  g0, bb0, threadIdx.x, sc1, sh1);
        bn_coef(stats + 128, stats + 192, g1, bb1, threadIdx.x, sc2, sh2);
    }
    __syncthreads();
    const int row = blockIdx.x * 256 + threadIdx.x;
    float x[9];
    gather_row(xyz, pts, outc, gidx, row, x);
    float x2[64];
    #pragma unroll
    for (int j = 0; j < 64; ++j){
        float acc = b0f[j];
        #pragma unroll
        for (int k = 0; k < 9; ++k) acc = fmaf(x[k], W0f[j*9+k], acc);
        x2[j] = fmaxf(fmaf(acc, sc1[j], sh1[j]), 0.f);
    }
    float x3[64];
    #pragma unroll
    for (int j = 0; j < 64; ++j){
        float a0 = b1f[j], a1 = 0.f, a2 = 0.f, a3 = 0.f;
        const float* wrow = W1f + j * 64;
        #pragma unroll
        for (int k = 0; k < 64; k += 4){
            a0 = fmaf(x2[k+0], wrow[k+0], a0);
            a1 = fmaf(x2[k+1], wrow[k+1], a1);
            a2 = fmaf(x2[k+2], wrow[k+2], a2);
            a3 = fmaf(x2[k+3], wrow[k+3], a3);
        }
        x3[j] = fmaxf(fmaf((a0 + a1) + (a2 + a3), sc2[j], sh2[j]), 0.f);
    }
    const int ch = threadIdx.x & 63, qq = threadIdx.x >> 6;
    for (int half = 0; half < 2; ++half){
        for (int c64 = 0; c64 < 64; ++c64){
            int c = half * 64 + c64;
            float a0 = b2f[c], a1 = 0.f, a2 = 0.f, a3 = 0.f;
            const float* wrow = W2f + c * 64;
            #pragma unroll
            for (int k = 0; k < 64; k += 4){
                a0 = fmaf(x3[k+0], wrow[k+0], a0);
                a1 = fmaf(x3[k+1], wrow[k+1], a1);
                a2 = fmaf(x3[k+2], wrow[k+2], a2);
                a3 = fmaf(x3[k+3], wrow[k+3], a3);
            }
            tr[threadIdx.x * 65 + c64] = (a0 + a1) + (a2 + a3);
        }
        __syncthreads();
        // quarter qq = rows [qq*64, qq*64+64) = groups 2qq (first 32 rows) and 2qq+1
        float s = 0.f, q = 0.f;
        float mxA = -1e30f, mnA = 1e30f, mxB = -1e30f, mnB = 1e30f;
        for (int r = 0; r < 32; ++r){
            float v = tr[(qq * 64 + r) * 65 + ch];
            s += v; q = fmaf(v, v, q);
            mxA = fmaxf(mxA, v); mnA = fminf(mnA, v);
        }
        for (int r = 32; r < 64; ++r){
            float v = tr[(qq * 64 + r) * 65 + ch];
            s += v; q = fmaf(v, v, q);
            mxB = fmaxf(mxB, v); mnB = fminf(mnB, v);
        }
        int c = half * 64 + ch;
        int gA = blockIdx.x * 8 + 2 * qq;
        pmax[(size_t)gA * 128 + c] = mxA;           // coalesced across lanes (c consecutive)
        pmin[(size_t)gA * 128 + c] = mnA;
        pmax[(size_t)(gA + 1) * 128 + c] = mxB;
        pmin[(size_t)(gA + 1) * 128 + c] = mnB;
        accs[qq][ch] = s; accq[qq][ch] = q;
        __syncthreads();
        if (threadIdx.x < 64){
            int cc = half * 64 + threadIdx.x;
            atomicAdd(&stats[256 + cc], (accs[0][threadIdx.x] + accs[1][threadIdx.x])
                                      + (accs[2][threadIdx.x] + accs[3][threadIdx.x]));
        } else if (threadIdx.x < 128){
            int t = threadIdx.x - 64;
            int cc = half * 64 + t;
            atomicAdd(&stats[384 + cc], (accq[0][t] + accq[1][t]) + (accq[2][t] + accq[3][t]));
        }
        __syncthreads();   // tr + accs reuse protection for next half
    }
}

// ---------------- BN3 applied to group max/min, relu, write out region 1 (f32) ----------------
__global__ __launch_bounds__(256) void pool_kernel(const float* __restrict__ stats,
                                                   const float* __restrict__ g2, const float* __restrict__ bb2,
                                                   const float* __restrict__ pmax, const float* __restrict__ pmin,
                                                   float* __restrict__ out){
    __shared__ float sc[128], sh[128];
    if (threadIdx.x < 128) bn_coef(stats + 256, stats + 384, g2, bb2, threadIdx.x, sc, sh);
    __syncthreads();
    int o = blockIdx.x * 256 + threadIdx.x;   // o = g*128 + ch, o < NGRP*128
    int ch = o & 127;
    float a = fmaf(pmax[o], sc[ch], sh[ch]);
    float b = fmaf(pmin[o], sc[ch], sh[ch]);  // affine maps interval endpoints (sc<0 covered)
    out[NGRP * 3 + o] = fmaxf(fmaxf(a, b), 0.0f);
}

extern "C" void kernel_launch(void* const* d_in, const int* in_sizes, int n_in,
                              void* d_out, int out_size, void* d_ws, size_t ws_size,
                              hipStream_t stream){
    const float* xyz = (const float*)d_in[0];
    const float* pts = (const float*)d_in[1];
    const float* W0  = (const float*)d_in[2];
    const float* b0  = (const float*)d_in[3];
    const float* g0  = (const float*)d_in[4];
    const float* bb0 = (const float*)d_in[5];
    const float* W1  = (const float*)d_in[6];
    const float* b1  = (const float*)d_in[7];
    const float* g1  = (const float*)d_in[8];
    const float* bb1 = (const float*)d_in[9];
    const float* W2  = (const float*)d_in[10];
    const float* b2  = (const float*)d_in[11];
    const float* g2  = (const float*)d_in[12];
    const float* bb2 = (const float*)d_in[13];
    float* out = (float*)d_out;   // f32 outputs: [new_xyz 49152 | new_points 2097152]

    // ws layout (bytes): stats[512f]@0 | gidx[524288 u16]@2048 |
    //                    pmax[2097152f]@1050624 | pmin@9439232 ; total 17,827,840
    if (ws_size < 17827840u) return;
    char*  ws    = (char*)d_ws;
    float* stats = (float*)ws;
    u16*   gidx  = (u16*)  (ws + 2048);
    float* pmax  = (float*)(ws + 1050624);
    float* pmin  = (float*)(ws + 9439232);

    zero_kernel <<<1, 512, 0, stream>>>(stats);
    fps_kernel  <<<16, 256, 0, stream>>>(xyz, out);
    ballq_kernel<<<NGRP/4, 256, 0, stream>>>(xyz, out, gidx);
    stats1_kernel<<<256, 256, 0, stream>>>(xyz, pts, out, gidx, W0, b0, stats);
    stats2_kernel<<<ROWS/256, 256, 0, stream>>>(xyz, pts, out, gidx, W0, b0, W1, b1, g0, bb0, stats);
    stats3_kernel<<<ROWS/256, 256, 0, stream>>>(xyz, pts, out, gidx, W0, b0, W1, b1, W2, b2,
                                                g0, bb0, g1, bb1, stats, pmax, pmin);
    pool_kernel <<<NGRP*128/256, 256, 0, stream>>>(stats, g2, bb2, pmax, pmin, out);
}